// Round 4
// baseline (142.972 us; speedup 1.0000x reference)
//
#include <hip/hip_runtime.h>
#include <hip/hip_fp16.h>
#include <cmath>

#define NLOD 10

// Codebook sizes are certain at compile time: min(lod^2, 1024).
// (LOD 9 is float-boundary-uncertain between res 64/65, but
// min(64^2,1024) == min(65^2,1024) == 1024, so sizes are fixed.)
static constexpr int SIZES[NLOD]     = {49, 64, 121, 196, 324, 529, 900, 1024, 1024, 1024};
static constexpr int ENTRY_OFS[NLOD] = {0, 49, 113, 234, 430, 754, 1283, 2183, 3207, 4231};
static constexpr int TOTAL_ENTRIES   = 5255;
// LDS: 5255 entries * 8 B = 42040 B -> two 1024-thread blocks/CU (84 KB of 160 KB)

struct ResArr { int r[NLOD]; };

template <int SIZE>
__device__ __forceinline__ void level_accum(const __half* __restrict__ cb, int res,
                                            float px, float py, float pz,
                                            float& a0, float& a1, float& a2)
{
    const float s   = (float)(res - 1);
    const float fhi = (float)(res - 2);

    float fx = px * s, fy = py * s, fz = pz * s;

    // x0 = clip(floor(x), 0, res-2); w = x - x0   (matches reference exactly)
    float ffx = fminf(fmaxf(floorf(fx), 0.0f), fhi);   // floor + v_med3_f32
    float ffy = fminf(fmaxf(floorf(fy), 0.0f), fhi);
    float ffz = fminf(fmaxf(floorf(fz), 0.0f), fhi);
    float wx = fx - ffx, wy = fy - ffy, wz = fz - ffz;

    unsigned ux = (unsigned)(int)ffx;
    unsigned uy = (unsigned)(int)ffy;
    unsigned uz = (unsigned)(int)ffz;

    // Incremental hash terms: h = (x*1) ^ (y*P1) ^ (z*P2)
    const unsigned P1 = 2654435761u, P2 = 805459861u;
    unsigned hx0 = ux;
    unsigned hx1 = ux + 1u;
    unsigned hy0 = uy * P1;
    unsigned hy1 = hy0 + P1;
    unsigned hz0 = uz * P2;
    unsigned hz1 = hz0 + P2;

    unsigned hxy00 = hx0 ^ hy0, hxy01 = hx0 ^ hy1;
    unsigned hxy10 = hx1 ^ hy0, hxy11 = hx1 ^ hy1;

    float wx0 = 1.0f - wx, wy0 = 1.0f - wy, wz0 = 1.0f - wz;
    float w00 = wx0 * wy0, w01 = wx0 * wy, w10 = wx * wy0, w11 = wx * wy;

    // One ds_read_b64 per corner, then three v_fma_mix_f32 consuming the f16
    // halves IN PLACE via op_sel (no extract, no cvt). Numerically identical
    // to fmaf(__half2float(h), wt, acc): fpext exact + fused fma both ways.
    auto corner = [&](unsigned h, float wt) {
        unsigned idx = h % (unsigned)SIZE;  // constexpr divisor -> magic mul / AND
        uint2 raw = reinterpret_cast<const uint2*>(cb)[idx];
        // a0 += f16_lo(raw.x) * wt
        asm("v_fma_mix_f32 %0, %1, %2, %0 op_sel_hi:[1,0,0]"
            : "+v"(a0) : "v"(raw.x), "v"(wt));
        // a1 += f16_hi(raw.x) * wt
        asm("v_fma_mix_f32 %0, %1, %2, %0 op_sel:[1,0,0] op_sel_hi:[1,0,0]"
            : "+v"(a1) : "v"(raw.x), "v"(wt));
        // a2 += f16_lo(raw.y) * wt
        asm("v_fma_mix_f32 %0, %1, %2, %0 op_sel_hi:[1,0,0]"
            : "+v"(a2) : "v"(raw.y), "v"(wt));
    };

    // reference OFFSETS order: (i,j,k) for i in(0,1) j in(0,1) k in(0,1)
    corner(hxy00 ^ hz0, w00 * wz0);
    corner(hxy00 ^ hz1, w00 * wz);
    corner(hxy01 ^ hz0, w01 * wz0);
    corner(hxy01 ^ hz1, w01 * wz);
    corner(hxy10 ^ hz0, w10 * wz0);
    corner(hxy10 ^ hz1, w10 * wz);
    corner(hxy11 ^ hz0, w11 * wz0);
    corner(hxy11 ^ hz1, w11 * wz);
}

__global__ __launch_bounds__(1024, 8)
void hashgrid_kernel(const float* __restrict__ pts,
                     const float* __restrict__ c0, const float* __restrict__ c1,
                     const float* __restrict__ c2, const float* __restrict__ c3,
                     const float* __restrict__ c4, const float* __restrict__ c5,
                     const float* __restrict__ c6, const float* __restrict__ c7,
                     const float* __restrict__ c8, const float* __restrict__ c9,
                     float* __restrict__ out, int npts, ResArr res)
{
    __shared__ __half cbh[TOTAL_ENTRIES * 4];   // 42040 B

    // Stage + compress codebooks into LDS (once per block)
    {
        const float* srcs[NLOD] = {c0, c1, c2, c3, c4, c5, c6, c7, c8, c9};
#pragma unroll
        for (int L = 0; L < NLOD; ++L) {
            for (int e = threadIdx.x; e < SIZES[L]; e += blockDim.x) {
                const float* s = srcs[L] + e * 3;
                __half2* d = reinterpret_cast<__half2*>(cbh + (ENTRY_OFS[L] + e) * 4);
                d[0] = __floats2half2_rn(s[0], s[1]);
                d[1] = __floats2half2_rn(s[2], 0.0f);
            }
        }
    }
    __syncthreads();

    const int stride = gridDim.x * blockDim.x;
    for (int n = blockIdx.x * blockDim.x + threadIdx.x; n < npts; n += stride) {
        float px = pts[n * 3 + 0];
        float py = pts[n * 3 + 1];
        float pz = pts[n * 3 + 2];

        float a0 = 0.0f, a1 = 0.0f, a2 = 0.0f;

        level_accum<  49>(cbh + ENTRY_OFS[0] * 4, res.r[0], px, py, pz, a0, a1, a2);
        level_accum<  64>(cbh + ENTRY_OFS[1] * 4, res.r[1], px, py, pz, a0, a1, a2);
        level_accum< 121>(cbh + ENTRY_OFS[2] * 4, res.r[2], px, py, pz, a0, a1, a2);
        level_accum< 196>(cbh + ENTRY_OFS[3] * 4, res.r[3], px, py, pz, a0, a1, a2);
        level_accum< 324>(cbh + ENTRY_OFS[4] * 4, res.r[4], px, py, pz, a0, a1, a2);
        level_accum< 529>(cbh + ENTRY_OFS[5] * 4, res.r[5], px, py, pz, a0, a1, a2);
        level_accum< 900>(cbh + ENTRY_OFS[6] * 4, res.r[6], px, py, pz, a0, a1, a2);
        level_accum<1024>(cbh + ENTRY_OFS[7] * 4, res.r[7], px, py, pz, a0, a1, a2);
        level_accum<1024>(cbh + ENTRY_OFS[8] * 4, res.r[8], px, py, pz, a0, a1, a2);
        level_accum<1024>(cbh + ENTRY_OFS[9] * 4, res.r[9], px, py, pz, a0, a1, a2);

        out[n * 3 + 0] = a0;
        out[n * 3 + 1] = a1;
        out[n * 3 + 2] = a2;
    }
}

extern "C" void kernel_launch(void* const* d_in, const int* in_sizes, int n_in,
                              void* d_out, int out_size, void* d_ws, size_t ws_size,
                              hipStream_t stream)
{
    const float* pts = (const float*)d_in[0];
    const int npts = in_sizes[0] / 3;

    // Replicate numpy's exact double-precision LOD computation (glibc libm).
    ResArr ra;
    const double b = exp((log(64.0) - log(6.0)) / 9.0);
    for (int l = 0; l < NLOD; ++l)
        ra.r[l] = (int)(1.0 + floor(6.0 * pow(b, (double)l)));

    // 512 blocks x 1024 thr: 2 blocks/CU (84 KB LDS), 32 waves/CU, 64 blocks/XCD.
    hashgrid_kernel<<<dim3(512), dim3(1024), 0, stream>>>(
        pts,
        (const float*)d_in[1], (const float*)d_in[2], (const float*)d_in[3],
        (const float*)d_in[4], (const float*)d_in[5], (const float*)d_in[6],
        (const float*)d_in[7], (const float*)d_in[8], (const float*)d_in[9],
        (const float*)d_in[10],
        (float*)d_out, npts, ra);
}

// Round 5
// 139.434 us; speedup vs baseline: 1.0254x; 1.0254x over previous
//
#include <hip/hip_runtime.h>
#include <hip/hip_fp16.h>
#include <cmath>

#define NLOD 10

// Codebook sizes are certain at compile time: min(lod^2, 1024).
static constexpr int SIZES[NLOD]     = {49, 64, 121, 196, 324, 529, 900, 1024, 1024, 1024};
static constexpr int ENTRY_OFS[NLOD] = {0, 49, 113, 234, 430, 754, 1283, 2183, 3207, 4231};
static constexpr int TOTAL_ENTRIES   = 5255;
// LDS: 5255 entries * 8 B = 42040 B -> two 1024-thread blocks/CU (84 KB of 160 KB)

struct ResArr { int r[NLOD]; };

template <int SIZE>
__device__ __forceinline__ void level_accum(const __half* __restrict__ cb, int res,
                                            float px, float py, float pz,
                                            float& a0, float& a1, float& a2)
{
    constexpr bool POW2 = (SIZE & (SIZE - 1)) == 0;
    constexpr unsigned P1 = 2654435761u, P2 = 805459861u;

    const float s = (float)(res - 1);
    float fx = px * s, fy = py * s, fz = pz * s;

    // clip(floor(x),0,res-2) == floor(x) here, exactly: px in [0,1) so fx >= 0,
    // and fx = px*(res-1) can never round UP to res-1 (largest px = 1-2^-23
    // gives a product more than half an ulp below res-1 for every level's
    // res-1 in [6,64]). So the med3 clamp is a provable no-op -> plain floor.
    float gx = floorf(fx), gy = floorf(fy), gz = floorf(fz);
    float wx = fx - gx, wy = fy - gy, wz = fz - gz;

    unsigned ux = (unsigned)(int)gx;
    unsigned uy = (unsigned)(int)gy;
    unsigned uz = (unsigned)(int)gz;

    // Incremental hash terms: h = (x*1) ^ (y*P1) ^ (z*P2).
    // For pow2 SIZE, fold the *8 byte-scale into the components:
    // (h<<3) == (ux<<3)^(uy*(P1*8))^(uz*(P2*8))  (shift distributes over xor),
    // and idx*8 == (h<<3) & ((SIZE-1)*8)  -> saves the per-corner shift.
    unsigned hx0, hx1, hy0, hy1, hz0, hz1;
    if constexpr (POW2) {
        hx0 = ux << 3;        hx1 = hx0 + 8u;
        hy0 = uy * (P1 * 8u); hy1 = hy0 + (P1 * 8u);
        hz0 = uz * (P2 * 8u); hz1 = hz0 + (P2 * 8u);
    } else {
        hx0 = ux;       hx1 = ux + 1u;
        hy0 = uy * P1;  hy1 = hy0 + P1;
        hz0 = uz * P2;  hz1 = hz0 + P2;
    }
    unsigned h00 = hx0 ^ hy0, h01 = hx0 ^ hy1;
    unsigned h10 = hx1 ^ hy0, h11 = hx1 ^ hy1;

    float wx0 = 1.0f - wx, wy0 = 1.0f - wy, wz0 = 1.0f - wz;
    float w00 = wx0 * wy0, w01 = wx0 * wy, w10 = wx * wy0, w11 = wx * wy;

    // One ds_read_b64 per corner; three v_fma_mix_f32 consume the f16 halves
    // in place via op_sel (numerically identical to fpext+fma, both exact/fused).
    auto corner = [&](unsigned h, float wt) {
        uint2 raw;
        if constexpr (POW2) {
            unsigned addr = h & (unsigned)((SIZE - 1) * 8);
            raw = *reinterpret_cast<const uint2*>(reinterpret_cast<const char*>(cb) + addr);
        } else {
            unsigned idx = h % (unsigned)SIZE;   // constexpr divisor -> magic mul
            raw = reinterpret_cast<const uint2*>(cb)[idx];
        }
        asm("v_fma_mix_f32 %0, %1, %2, %0 op_sel_hi:[1,0,0]"
            : "+v"(a0) : "v"(raw.x), "v"(wt));
        asm("v_fma_mix_f32 %0, %1, %2, %0 op_sel:[1,0,0] op_sel_hi:[1,0,0]"
            : "+v"(a1) : "v"(raw.x), "v"(wt));
        asm("v_fma_mix_f32 %0, %1, %2, %0 op_sel_hi:[1,0,0]"
            : "+v"(a2) : "v"(raw.y), "v"(wt));
    };

    // reference OFFSETS order: (i,j,k) for i in(0,1) j in(0,1) k in(0,1)
    corner(h00 ^ hz0, w00 * wz0);
    corner(h00 ^ hz1, w00 * wz);
    corner(h01 ^ hz0, w01 * wz0);
    corner(h01 ^ hz1, w01 * wz);
    corner(h10 ^ hz0, w10 * wz0);
    corner(h10 ^ hz1, w10 * wz);
    corner(h11 ^ hz0, w11 * wz0);
    corner(h11 ^ hz1, w11 * wz);
}

__global__ __launch_bounds__(1024, 8)
void hashgrid_kernel(const float* __restrict__ pts,
                     const float* __restrict__ c0, const float* __restrict__ c1,
                     const float* __restrict__ c2, const float* __restrict__ c3,
                     const float* __restrict__ c4, const float* __restrict__ c5,
                     const float* __restrict__ c6, const float* __restrict__ c7,
                     const float* __restrict__ c8, const float* __restrict__ c9,
                     float* __restrict__ out, int npts, ResArr res)
{
    __shared__ __half cbh[TOTAL_ENTRIES * 4];   // 42040 B

    // Stage + compress codebooks into LDS (once per block)
    {
        const float* srcs[NLOD] = {c0, c1, c2, c3, c4, c5, c6, c7, c8, c9};
#pragma unroll
        for (int L = 0; L < NLOD; ++L) {
            for (int e = threadIdx.x; e < SIZES[L]; e += blockDim.x) {
                const float* s = srcs[L] + e * 3;
                __half2* d = reinterpret_cast<__half2*>(cbh + (ENTRY_OFS[L] + e) * 4);
                d[0] = __floats2half2_rn(s[0], s[1]);
                d[1] = __floats2half2_rn(s[2], 0.0f);
            }
        }
    }
    __syncthreads();

    // Two points per thread per iteration: 16 independent gathers in flight
    // per wave (vs 8), doubling latency hiding. Shapes: 512 blk x 1024 thr,
    // S = 524288, npts = 2M -> exactly 2 loop iterations for every thread.
    const int S = gridDim.x * blockDim.x;
    for (int n = blockIdx.x * blockDim.x + threadIdx.x; n < npts; n += 2 * S) {
        const int m = n + S;
        const bool hasB = (m < npts);
        const int mc = hasB ? m : n;      // clamp: B duplicates A, store suppressed

        float ax = pts[n * 3 + 0], ay = pts[n * 3 + 1], az = pts[n * 3 + 2];
        float bx = pts[mc * 3 + 0], by = pts[mc * 3 + 1], bz = pts[mc * 3 + 2];

        float A0 = 0.0f, A1 = 0.0f, A2 = 0.0f;
        float B0 = 0.0f, B1 = 0.0f, B2 = 0.0f;

#define LEVEL2(SZ, L)                                                              \
        level_accum<SZ>(cbh + ENTRY_OFS[L] * 4, res.r[L], ax, ay, az, A0, A1, A2); \
        level_accum<SZ>(cbh + ENTRY_OFS[L] * 4, res.r[L], bx, by, bz, B0, B1, B2);

        LEVEL2(  49, 0)
        LEVEL2(  64, 1)
        LEVEL2( 121, 2)
        LEVEL2( 196, 3)
        LEVEL2( 324, 4)
        LEVEL2( 529, 5)
        LEVEL2( 900, 6)
        LEVEL2(1024, 7)
        LEVEL2(1024, 8)
        LEVEL2(1024, 9)
#undef LEVEL2

        out[n * 3 + 0] = A0;
        out[n * 3 + 1] = A1;
        out[n * 3 + 2] = A2;
        if (hasB) {
            out[m * 3 + 0] = B0;
            out[m * 3 + 1] = B1;
            out[m * 3 + 2] = B2;
        }
    }
}

extern "C" void kernel_launch(void* const* d_in, const int* in_sizes, int n_in,
                              void* d_out, int out_size, void* d_ws, size_t ws_size,
                              hipStream_t stream)
{
    const float* pts = (const float*)d_in[0];
    const int npts = in_sizes[0] / 3;

    // Replicate numpy's exact double-precision LOD computation (glibc libm):
    // LOD 9 sits at 6*b^9 == 64.0 +/- ~1e-14, floor() is boundary-sensitive.
    ResArr ra;
    const double b = exp((log(64.0) - log(6.0)) / 9.0);
    for (int l = 0; l < NLOD; ++l)
        ra.r[l] = (int)(1.0 + floor(6.0 * pow(b, (double)l)));

    // 512 blocks x 1024 thr: 2 blocks/CU (84 KB LDS), 32 waves/CU.
    hashgrid_kernel<<<dim3(512), dim3(1024), 0, stream>>>(
        pts,
        (const float*)d_in[1], (const float*)d_in[2], (const float*)d_in[3],
        (const float*)d_in[4], (const float*)d_in[5], (const float*)d_in[6],
        (const float*)d_in[7], (const float*)d_in[8], (const float*)d_in[9],
        (const float*)d_in[10],
        (float*)d_out, npts, ra);
}